// Round 3
// baseline (121.792 us; speedup 1.0000x reference)
//
#include <hip/hip_runtime.h>
#include <math.h>

#define BB 1024   // batch
#define VV 256    // variables
#define KK 64     // categories
#define N0 8192   // input nodes
#define CC 32     // sum-node children

#define LOG2E 1.4426950408889634f
#define LN2   0.6931471805599453f
// layer-1 weight scale 2^13 centers linear-domain values near 2^0;
// accumulated scale at the root su is 2^(8*13) = 2^104.
#define W1SCALE 8192.0f
#define ROOT_LOG2_SCALE 104.0f

static __device__ __forceinline__ float flog2(float x) { return __builtin_amdgcn_logf(x); }
static __device__ __forceinline__ float bf2f(unsigned short u) {
    union { unsigned int i; float f; } c; c.i = (unsigned int)u << 16; return c.f;
}
static __device__ __forceinline__ unsigned short f2bf(float f) {
    union { float f; unsigned int i; } c; c.f = f;
    unsigned int r = c.i + 0x7FFFu + ((c.i >> 16) & 1u);  // RNE
    return (unsigned short)(r >> 16);
}
// bf16 in lo16 of u32 -> f32 (1 shift)
static __device__ __forceinline__ float lo_f(unsigned int u) {
    union { unsigned int i; float f; } c; c.i = u << 16; return c.f;
}
// bf16 in hi16 of u32 -> f32 (1 and)
static __device__ __forceinline__ float hi_f(unsigned int u) {
    union { unsigned int i; float f; } c; c.i = u & 0xFFFF0000u; return c.f;
}
// pack two f32 -> two bf16 in one u32 (verified on gfx950: T12/m214v22).
// Even if lo/hi order were swapped, the swap cancels layer-internally.
static __device__ __forceinline__ unsigned int cvtpk(float a, float b) {
    unsigned int r;
    asm("v_cvt_pk_bf16_f32 %0, %1, %2" : "=v"(r) : "v"(a), "v"(b));
    return r;
}

// ---------------------------------------------------------------------------
// prep (linear domain, BYTE-OFFSET indices: all local ids *8, fits u16):
//  bid <  2048 : lpT[k][i] = softmax(in_logits[i])[k]      (bf16, TRANSPOSED)
//  bid <  2944 : spk[n][c] = (cid*8) | (bf16 lin-weight <<16); layer1 w *= 2^13
//  bid <  3000 : ppk[e]    = (p0*8) | ((p1*8) << 16)
//  bid == 3000 : rpk[c]    = {p0*8, p1*8, bf16 softmax(w4), 0}
// ---------------------------------------------------------------------------
__global__ void __launch_bounds__(256) k_prep(
        const float* __restrict__ logits,
        const float* __restrict__ w1, const float* __restrict__ w2,
        const float* __restrict__ w3, const float* __restrict__ w4,
        const int* __restrict__ cids1, const int* __restrict__ cids2,
        const int* __restrict__ cids3, const int* __restrict__ cids4,
        const int* __restrict__ pids1, const int* __restrict__ pids2,
        const int* __restrict__ pids3, const int* __restrict__ pids4,
        unsigned short* __restrict__ lpT, unsigned int* __restrict__ ppk,
        unsigned int* __restrict__ spk, ushort4* __restrict__ rpk) {
    int bid = blockIdx.x, tid = threadIdx.x;
    __shared__ unsigned short tile[4][64];
    if (bid < 2048) {
        int i = bid * 4 + (tid >> 6);
        int k = tid & 63;
        float l = logits[(size_t)i * KK + k];
        float m = l;
        #pragma unroll
        for (int d = 32; d; d >>= 1) m = fmaxf(m, __shfl_xor(m, d));
        float e = __expf(l - m);
        float s = e;
        #pragma unroll
        for (int d = 32; d; d >>= 1) s += __shfl_xor(s, d);
        tile[tid >> 6][k] = f2bf(e / s);          // linear softmax prob
        __syncthreads();
        if (tid < 64) {  // transposed store: 4 consecutive i per k
            ushort4 o;
            o.x = tile[0][tid]; o.y = tile[1][tid];
            o.z = tile[2][tid]; o.w = tile[3][tid];
            *(ushort4*)(lpT + (size_t)tid * N0 + bid * 4) = o;
        }
    } else if (bid < 2944) {
        int n = (bid - 2048) * 8 + (tid >> 5);
        int lane = tid & 31;
        if (n < 7168) {
            const float* wsrc; const int* csrc; float scale;
            if (n < 4096)      { wsrc = w1 + (size_t)n * CC;          csrc = cids1 + (size_t)n * CC;          scale = W1SCALE; }
            else if (n < 6144) { wsrc = w2 + (size_t)(n - 4096) * CC; csrc = cids2 + (size_t)(n - 4096) * CC; scale = 1.0f; }
            else               { wsrc = w3 + (size_t)(n - 6144) * CC; csrc = cids3 + (size_t)(n - 6144) * CC; scale = 1.0f; }
            float lw = wsrc[lane];
            float m = lw;
            #pragma unroll
            for (int d = 16; d; d >>= 1) m = fmaxf(m, __shfl_xor(m, d, 32));
            float e = __expf(lw - m);
            float s = e;
            #pragma unroll
            for (int d = 16; d; d >>= 1) s += __shfl_xor(s, d, 32);
            unsigned int cid8 = (unsigned int)(csrc[lane] - 1) * 8u;
            spk[(size_t)n * CC + lane] = cid8 | ((unsigned int)f2bf(e / s * scale) << 16);
        }
    } else if (bid < 3000) {
        int idx = (bid - 2944) * 256 + tid;  // 14336 elements total
        int p0, p1;
        if (idx < 8192)       { p0 = pids1[idx * 2] - 1;                p1 = pids1[idx * 2 + 1] - 1; }
        else if (idx < 12288) { int e = idx - 8192;  p0 = pids2[e * 2] - 8193;  p1 = pids2[e * 2 + 1] - 8193; }
        else                  { int e = idx - 12288; p0 = pids3[e * 2] - 12289; p1 = pids3[e * 2 + 1] - 12289; }
        ppk[idx] = ((unsigned int)p0 * 8u) | (((unsigned int)p1 * 8u) << 16);
    } else {
        if (tid < CC) {
            float lw = w4[tid];
            float m = lw;
            #pragma unroll
            for (int d = 16; d; d >>= 1) m = fmaxf(m, __shfl_xor(m, d, 32));
            float e = __expf(lw - m);
            float s = e;
            #pragma unroll
            for (int d = 16; d; d >>= 1) s += __shfl_xor(s, d, 32);
            int el = cids4[tid] - 1;
            ushort4 r;
            r.x = (unsigned short)((pids4[el * 2]     - 14337) * 8);
            r.y = (unsigned short)((pids4[el * 2 + 1] - 14337) * 8);
            r.z = f2bf(e / s); r.w = 0;
            rpk[tid] = r;
        }
    }
}

// process one sum node given its 8 preloaded spk words; identical FMA order
// to the round-2 kernel (children ascending, chunks of 8).
static __device__ __forceinline__ void sum_node(
        const char* emB, const uint4* __restrict__ q,
        float& s0, float& s1, float& s2, float& s3) {
    #pragma unroll
    for (int h = 0; h < 4; ++h) {
        unsigned int idx[8] = { q[h * 2].x, q[h * 2].y, q[h * 2].z, q[h * 2].w,
                                q[h * 2 + 1].x, q[h * 2 + 1].y, q[h * 2 + 1].z, q[h * 2 + 1].w };
        uint2 t[8];
        #pragma unroll
        for (int c = 0; c < 8; ++c)
            t[c] = *(const uint2*)(emB + (idx[c] & 0xFFFFu));
        #pragma unroll
        for (int c = 0; c < 8; ++c) {
            float w = hi_f(idx[c]);
            s0 = fmaf(lo_f(t[c].x), w, s0);
            s1 = fmaf(hi_f(t[c].x), w, s1);
            s2 = fmaf(lo_f(t[c].y), w, s2);
            s3 = fmaf(hi_f(t[c].y), w, s3);
        }
    }
}

// ---------------------------------------------------------------------------
// One layer for a 4-column slice, linear domain.
// prod: em[e] = nm[p0]*nm[p1], 4 elements batched, cvt_pk packed stores.
// sum: spk index-loads are software-pipelined one node ahead (double-buffered
// in registers), so the ~300-cycle L2/L3 latency hides under the previous
// node's 32 LDS gathers + FMAs. S is always a multiple of nthr, so the
// pipeline control is wave-uniform. Indices are byte offsets (*8 in prep).
// ---------------------------------------------------------------------------
template <typename NMP>
static __device__ __forceinline__ void do_layer(
        NMP nm4, uint2* em4,
        const unsigned int* __restrict__ pp, const unsigned int* __restrict__ sp,
        int E, int S, int tid, int nthr) {
    const char* nmB = (const char*)nm4;
    const char* emB = (const char*)em4;
    for (int e = tid; e < E; e += nthr * 4) {
        unsigned int pw[4];
        uint2 av[4], bv[4];
        int cnt = 0;
        #pragma unroll
        for (int j = 0; j < 4; ++j) {
            int ee = e + j * nthr;
            if (ee < E) { pw[j] = pp[ee]; ++cnt; }
        }
        #pragma unroll
        for (int j = 0; j < 4; ++j) {
            if (j < cnt) {
                av[j] = *(const uint2*)(nmB + (pw[j] & 0xFFFFu));
                bv[j] = *(const uint2*)(nmB + (pw[j] >> 16));
            }
        }
        #pragma unroll
        for (int j = 0; j < 4; ++j) {
            if (j < cnt) {
                uint2 o;
                o.x = cvtpk(lo_f(av[j].x) * lo_f(bv[j].x),
                            hi_f(av[j].x) * hi_f(bv[j].x));
                o.y = cvtpk(lo_f(av[j].y) * lo_f(bv[j].y),
                            hi_f(av[j].y) * hi_f(bv[j].y));
                em4[e + j * nthr] = o;
            }
        }
    }
    __syncthreads();
    {
        // S is a multiple of nthr: every thread runs S/nthr iterations.
        int s = tid;
        const uint4* base = (const uint4*)(sp + (size_t)s * CC);
        uint4 q[8];
        #pragma unroll
        for (int j = 0; j < 8; ++j) q[j] = base[j];
        while (true) {
            bool more = (s + nthr < S);
            uint4 qn[8];
            if (more) {
                const uint4* bn = (const uint4*)(sp + (size_t)(s + nthr) * CC);
                #pragma unroll
                for (int j = 0; j < 8; ++j) qn[j] = bn[j];
            }
            float s0 = 0.f, s1 = 0.f, s2 = 0.f, s3 = 0.f;
            sum_node(emB, q, s0, s1, s2, s3);
            uint2 o;
            o.x = cvtpk(s0, s1);
            o.y = cvtpk(s2, s3);
            nm4[s] = o;
            if (!more) break;
            #pragma unroll
            for (int j = 0; j < 8; ++j) q[j] = qn[j];
            s += nthr;
        }
    }
    __syncthreads();
}

// root: 128 threads (32 children x 4 cols), shfl-xor reduce within 32-groups.
template <typename NMP>
static __device__ __forceinline__ void do_root(NMP nm4, const ushort4* __restrict__ rpk,
                                               float* __restrict__ out, int b0, int tid) {
    const char* nmB = (const char*)nm4;
    if (tid < 128) {
        int col = tid >> 5, c = tid & 31;
        ushort4 r = rpk[c];
        int woff = (col >> 1) << 2;  // which u32 word holds this column pair
        unsigned int wa = *(const unsigned int*)(nmB + r.x + woff);
        unsigned int wb = *(const unsigned int*)(nmB + r.y + woff);
        float va = (col & 1) ? hi_f(wa) : lo_f(wa);
        float vb = (col & 1) ? hi_f(wb) : lo_f(wb);
        float su = va * vb * bf2f(r.z);
        #pragma unroll
        for (int d = 16; d; d >>= 1) su += __shfl_xor(su, d);
        if (c == 0) out[b0 + col] = (flog2(su) - ROOT_LOG2_SCALE) * LN2;
    }
}

// ---------------------------------------------------------------------------
// mega A: block owns 4 batch cols; em AND nm slices in LDS (135 KB, dynamic
// opt-in). em at LDS offset 0 so the hot sum-gathers fold their base.
// 1024 threads, launch_bounds(1024,4) pins VGPR<=128 (16 waves/CU kept).
// ---------------------------------------------------------------------------
__global__ void __launch_bounds__(1024, 4) k_mega_lds(
        const int* __restrict__ x, const unsigned short* __restrict__ lpT,
        const unsigned int* __restrict__ ppk, const unsigned int* __restrict__ spk,
        const ushort4* __restrict__ rpk, float* __restrict__ out) {
    extern __shared__ uint2 smem2[];
    uint2* em4 = smem2;                   // [8192] = 64 KB (offset 0: hot gathers)
    uint2* nm4 = smem2 + 8192;            // [8192] = 64 KB
    int* xv = (int*)(smem2 + 16384);      // [4][256] = 4 KB
    int tid = threadIdx.x;
    int b0 = blockIdx.x * 4;

    {
        int c = tid >> 8, v = tid & 255;
        xv[tid] = x[(b0 + c) * VV + v];
    }
    __syncthreads();
    for (int i = tid; i < N0; i += 1024) {   // input gather via transposed lpT
        int v = i >> 5;
        unsigned int a = lpT[(size_t)xv[v]       * N0 + i];
        unsigned int b = lpT[(size_t)xv[256 + v] * N0 + i];
        unsigned int c = lpT[(size_t)xv[512 + v] * N0 + i];
        unsigned int d = lpT[(size_t)xv[768 + v] * N0 + i];
        uint2 o;
        o.x = a | (b << 16);
        o.y = c | (d << 16);
        nm4[i] = o;
    }
    __syncthreads();
    do_layer(nm4, em4, ppk,         spk,          8192, 4096, tid, 1024);
    do_layer(nm4, em4, ppk + 8192,  spk + 131072, 4096, 2048, tid, 1024);
    do_layer(nm4, em4, ppk + 12288, spk + 196608, 2048, 1024, tid, 1024);
    do_root(nm4, rpk, out, b0, tid);
}

// ---------------------------------------------------------------------------
// mega B (fallback if >64KB LDS opt-in fails): em in LDS (64 KB), nm in a
// per-block global slice.
// ---------------------------------------------------------------------------
__global__ void __launch_bounds__(1024, 4) k_mega_glb(
        const int* __restrict__ x, const unsigned short* __restrict__ lpT,
        const unsigned int* __restrict__ ppk, const unsigned int* __restrict__ spk,
        const ushort4* __restrict__ rpk, uint2* __restrict__ nmg,
        float* __restrict__ out) {
    extern __shared__ uint2 smem2[];
    uint2* em4 = smem2;                                // [8192] = 64 KB
    uint2* nm4 = nmg + (size_t)blockIdx.x * 8192;      // global slice
    int tid = threadIdx.x;
    int b0 = blockIdx.x * 4;

    for (int i = tid; i < N0; i += 1024) {
        int v = i >> 5;
        unsigned int a = lpT[(size_t)x[(b0 + 0) * VV + v] * N0 + i];
        unsigned int b = lpT[(size_t)x[(b0 + 1) * VV + v] * N0 + i];
        unsigned int c = lpT[(size_t)x[(b0 + 2) * VV + v] * N0 + i];
        unsigned int d = lpT[(size_t)x[(b0 + 3) * VV + v] * N0 + i];
        uint2 o;
        o.x = a | (b << 16);
        o.y = c | (d << 16);
        nm4[i] = o;
    }
    __syncthreads();
    do_layer(nm4, em4, ppk,         spk,          8192, 4096, tid, 1024);
    do_layer(nm4, em4, ppk + 8192,  spk + 131072, 4096, 2048, tid, 1024);
    do_layer(nm4, em4, ppk + 12288, spk + 196608, 2048, 1024, tid, 1024);
    do_root(nm4, rpk, out, b0, tid);
}

// ---------------------------------------------------------------------------
// Launch: 2 dispatches (prep + mega). Deterministic A/B pick by whether the
// 135 KB dynamic-LDS opt-in succeeds.
// ---------------------------------------------------------------------------
extern "C" void kernel_launch(void* const* d_in, const int* in_sizes, int n_in,
                              void* d_out, int out_size, void* d_ws, size_t ws_size,
                              hipStream_t stream) {
    const int*   x         = (const int*)  d_in[0];
    const float* in_logits = (const float*)d_in[1];
    const float* w1        = (const float*)d_in[2];
    const float* w2        = (const float*)d_in[3];
    const float* w3        = (const float*)d_in[4];
    const float* w4        = (const float*)d_in[5];
    const int*   pids1     = (const int*)  d_in[6];
    const int*   pids2     = (const int*)  d_in[7];
    const int*   pids3     = (const int*)  d_in[8];
    const int*   pids4     = (const int*)  d_in[9];
    const int*   cids1     = (const int*)  d_in[10];
    const int*   cids2     = (const int*)  d_in[11];
    const int*   cids3     = (const int*)  d_in[12];
    const int*   cids4     = (const int*)  d_in[13];
    float* out = (float*)d_out;

    char* ws = (char*)d_ws;
    unsigned short* lpT = (unsigned short*)ws;                    // 64*8192 bf16 = 1 MB
    unsigned int*   ppk = (unsigned int*)(ws + 1048576);          // 14336 u32
    unsigned int*   spk = (unsigned int*)(ws + 1105920);          // 229376 u32
    ushort4*        rpk = (ushort4*)(ws + 2023424);               // 32 x 8 B
    uint2*          nmg = (uint2*)(ws + 2023936);                 // 256*8192*8 B = 16 MB (B only)

    k_prep<<<3001, 256, 0, stream>>>(in_logits, w1, w2, w3, w4,
                                     cids1, cids2, cids3, cids4,
                                     pids1, pids2, pids3, pids4,
                                     lpT, ppk, spk, rpk);

    const int SMEM_A = 135168;  // 64K em + 64K nm + 4K xv
    const int SMEM_B = 65536;   // 64K em
    hipError_t e = hipFuncSetAttribute((const void*)k_mega_lds,
                                       hipFuncAttributeMaxDynamicSharedMemorySize, SMEM_A);
    if (e == hipSuccess) {
        k_mega_lds<<<256, 1024, SMEM_A, stream>>>(x, lpT, ppk, spk, rpk, out);
    } else {
        (void)hipGetLastError();  // clear sticky error from failed opt-in
        hipFuncSetAttribute((const void*)k_mega_glb,
                            hipFuncAttributeMaxDynamicSharedMemorySize, SMEM_B);
        k_mega_glb<<<256, 1024, SMEM_B, stream>>>(x, lpT, ppk, spk, rpk, nmg, out);
    }
}

// Round 4
// 118.156 us; speedup vs baseline: 1.0308x; 1.0308x over previous
//
#include <hip/hip_runtime.h>
#include <math.h>

#define BB 1024   // batch
#define VV 256    // variables
#define KK 64     // categories
#define N0 8192   // input nodes
#define CC 32     // sum-node children

#define LOG2E 1.4426950408889634f
#define LN2   0.6931471805599453f
// layer-1 weight scale 2^13 centers linear-domain values near 2^0;
// accumulated scale at the root su is 2^(8*13) = 2^104.
#define W1SCALE 8192.0f
#define ROOT_LOG2_SCALE 104.0f

static __device__ __forceinline__ float flog2(float x) { return __builtin_amdgcn_logf(x); }
static __device__ __forceinline__ float bf2f(unsigned short u) {
    union { unsigned int i; float f; } c; c.i = (unsigned int)u << 16; return c.f;
}
static __device__ __forceinline__ unsigned short f2bf(float f) {
    union { float f; unsigned int i; } c; c.f = f;
    unsigned int r = c.i + 0x7FFFu + ((c.i >> 16) & 1u);  // RNE
    return (unsigned short)(r >> 16);
}
// bf16 in lo16 of u32 -> f32 (1 shift)
static __device__ __forceinline__ float lo_f(unsigned int u) {
    union { unsigned int i; float f; } c; c.i = u << 16; return c.f;
}
// bf16 in hi16 of u32 -> f32 (1 and)
static __device__ __forceinline__ float hi_f(unsigned int u) {
    union { unsigned int i; float f; } c; c.i = u & 0xFFFF0000u; return c.f;
}
// pack two f32 -> two bf16 in one u32 (verified on gfx950: T12/m214v22).
static __device__ __forceinline__ unsigned int cvtpk(float a, float b) {
    unsigned int r;
    asm("v_cvt_pk_bf16_f32 %0, %1, %2" : "=v"(r) : "v"(a), "v"(b));
    return r;
}

// ---------------------------------------------------------------------------
// prep (linear domain, BYTE-OFFSET indices: all local ids *8, fits u16):
//  bid <  512 : lpT[k][i] = softmax(in_logits[i])[k]  (bf16, TRANSPOSED), 16 nodes/blk
//  bid <  960 : spk[n][c] = (cid*8) | (bf16 lin-weight <<16); layer1 w *= 2^13
//  bid <  974 : ppk[e]    = (p0*8) | ((p1*8) << 16)   (1024 elems/blk)
//  bid == 974 : rpk[c]    = {p0*8, p1*8, bf16 softmax(w4), 0}
// Grid shrunk 3001 -> 975 blocks (round-4: prep was block-overhead-bound).
// ---------------------------------------------------------------------------
__global__ void __launch_bounds__(256) k_prep(
        const float* __restrict__ logits,
        const float* __restrict__ w1, const float* __restrict__ w2,
        const float* __restrict__ w3, const float* __restrict__ w4,
        const int* __restrict__ cids1, const int* __restrict__ cids2,
        const int* __restrict__ cids3, const int* __restrict__ cids4,
        const int* __restrict__ pids1, const int* __restrict__ pids2,
        const int* __restrict__ pids3, const int* __restrict__ pids4,
        unsigned short* __restrict__ lpT, unsigned int* __restrict__ ppk,
        unsigned int* __restrict__ spk, ushort4* __restrict__ rpk) {
    int bid = blockIdx.x, tid = threadIdx.x;
    __shared__ unsigned short tile[16][64];
    if (bid < 512) {
        int k = tid & 63;
        int w = tid >> 6;                 // wave id, owns rows w*4 .. w*4+3
        #pragma unroll
        for (int r = 0; r < 4; ++r) {
            int row = w * 4 + r;
            int i = bid * 16 + row;
            float l = logits[(size_t)i * KK + k];
            float m = l;
            #pragma unroll
            for (int d = 32; d; d >>= 1) m = fmaxf(m, __shfl_xor(m, d));
            float e = __expf(l - m);
            float s = e;
            #pragma unroll
            for (int d = 32; d; d >>= 1) s += __shfl_xor(s, d);
            tile[row][k] = f2bf(e / s);   // linear softmax prob
        }
        __syncthreads();
        if (tid < 128) {  // 16B transposed stores: 8 consecutive nodes per k
            int kk = tid & 63, g = tid >> 6;
            uint4 o;
            o.x = (unsigned int)tile[g * 8 + 0][kk] | ((unsigned int)tile[g * 8 + 1][kk] << 16);
            o.y = (unsigned int)tile[g * 8 + 2][kk] | ((unsigned int)tile[g * 8 + 3][kk] << 16);
            o.z = (unsigned int)tile[g * 8 + 4][kk] | ((unsigned int)tile[g * 8 + 5][kk] << 16);
            o.w = (unsigned int)tile[g * 8 + 6][kk] | ((unsigned int)tile[g * 8 + 7][kk] << 16);
            *(uint4*)(lpT + (size_t)kk * N0 + bid * 16 + g * 8) = o;
        }
    } else if (bid < 960) {
        int group = tid >> 5;
        int lane = tid & 31;
        #pragma unroll
        for (int r = 0; r < 2; ++r) {
            int n = (bid - 512) * 16 + group * 2 + r;   // 448*16 = 7168 exact
            const float* wsrc; const int* csrc; float scale;
            if (n < 4096)      { wsrc = w1 + (size_t)n * CC;          csrc = cids1 + (size_t)n * CC;          scale = W1SCALE; }
            else if (n < 6144) { wsrc = w2 + (size_t)(n - 4096) * CC; csrc = cids2 + (size_t)(n - 4096) * CC; scale = 1.0f; }
            else               { wsrc = w3 + (size_t)(n - 6144) * CC; csrc = cids3 + (size_t)(n - 6144) * CC; scale = 1.0f; }
            float lw = wsrc[lane];
            float m = lw;
            #pragma unroll
            for (int d = 16; d; d >>= 1) m = fmaxf(m, __shfl_xor(m, d, 32));
            float e = __expf(lw - m);
            float s = e;
            #pragma unroll
            for (int d = 16; d; d >>= 1) s += __shfl_xor(s, d, 32);
            unsigned int cid8 = (unsigned int)(csrc[lane] - 1) * 8u;
            spk[(size_t)n * CC + lane] = cid8 | ((unsigned int)f2bf(e / s * scale) << 16);
        }
    } else if (bid < 974) {
        int b = bid - 960;
        #pragma unroll
        for (int j = 0; j < 4; ++j) {
            int idx = b * 1024 + j * 256 + tid;  // 14*1024 = 14336 exact
            int p0, p1;
            if (idx < 8192)       { p0 = pids1[idx * 2] - 1;                p1 = pids1[idx * 2 + 1] - 1; }
            else if (idx < 12288) { int e = idx - 8192;  p0 = pids2[e * 2] - 8193;  p1 = pids2[e * 2 + 1] - 8193; }
            else                  { int e = idx - 12288; p0 = pids3[e * 2] - 12289; p1 = pids3[e * 2 + 1] - 12289; }
            ppk[idx] = ((unsigned int)p0 * 8u) | (((unsigned int)p1 * 8u) << 16);
        }
    } else {
        if (tid < CC) {
            float lw = w4[tid];
            float m = lw;
            #pragma unroll
            for (int d = 16; d; d >>= 1) m = fmaxf(m, __shfl_xor(m, d, 32));
            float e = __expf(lw - m);
            float s = e;
            #pragma unroll
            for (int d = 16; d; d >>= 1) s += __shfl_xor(s, d, 32);
            int el = cids4[tid] - 1;
            ushort4 r;
            r.x = (unsigned short)((pids4[el * 2]     - 14337) * 8);
            r.y = (unsigned short)((pids4[el * 2 + 1] - 14337) * 8);
            r.z = f2bf(e / s); r.w = 0;
            rpk[tid] = r;
        }
    }
}

// ---------------------------------------------------------------------------
// One layer for a 4-column slice, linear domain.  (round-2 form, verified
// fastest: the round-3 explicit load pipeline regressed — compiler
// re-schedules it anyway.)
// prod: em[e] = nm[p0]*nm[p1], 4 elements batched, cvt_pk packed stores.
// sum: per node, 8 global uint4 loads; children gathered in TWO chunks of
// 16 ds_read_b64 each, then unpack + fmaf per child. Indices are byte
// offsets (pre-scaled *8 in prep).
// ---------------------------------------------------------------------------
template <typename NMP>
static __device__ __forceinline__ void do_layer(
        NMP nm4, uint2* em4,
        const unsigned int* __restrict__ pp, const unsigned int* __restrict__ sp,
        int E, int S, int tid, int nthr) {
    const char* nmB = (const char*)nm4;
    const char* emB = (const char*)em4;
    for (int e = tid; e < E; e += nthr * 4) {
        unsigned int pw[4];
        uint2 av[4], bv[4];
        int cnt = 0;
        #pragma unroll
        for (int j = 0; j < 4; ++j) {
            int ee = e + j * nthr;
            if (ee < E) { pw[j] = pp[ee]; ++cnt; }
        }
        #pragma unroll
        for (int j = 0; j < 4; ++j) {
            if (j < cnt) {
                av[j] = *(const uint2*)(nmB + (pw[j] & 0xFFFFu));
                bv[j] = *(const uint2*)(nmB + (pw[j] >> 16));
            }
        }
        #pragma unroll
        for (int j = 0; j < 4; ++j) {
            if (j < cnt) {
                uint2 o;
                o.x = cvtpk(lo_f(av[j].x) * lo_f(bv[j].x),
                            hi_f(av[j].x) * hi_f(bv[j].x));
                o.y = cvtpk(lo_f(av[j].y) * lo_f(bv[j].y),
                            hi_f(av[j].y) * hi_f(bv[j].y));
                em4[e + j * nthr] = o;
            }
        }
    }
    __syncthreads();
    for (int s = tid; s < S; s += nthr) {
        const uint4* base = (const uint4*)(sp + (size_t)s * CC);
        uint4 q[8];
        #pragma unroll
        for (int j = 0; j < 8; ++j) q[j] = base[j];
        unsigned int uu[32];
        #pragma unroll
        for (int j = 0; j < 8; ++j) {
            uu[j * 4 + 0] = q[j].x; uu[j * 4 + 1] = q[j].y;
            uu[j * 4 + 2] = q[j].z; uu[j * 4 + 3] = q[j].w;
        }
        float s0 = 0.f, s1 = 0.f, s2 = 0.f, s3 = 0.f;
        #pragma unroll
        for (int h = 0; h < 2; ++h) {
            uint2 t[16];
            #pragma unroll
            for (int c = 0; c < 16; ++c)
                t[c] = *(const uint2*)(emB + (uu[h * 16 + c] & 0xFFFFu));
            #pragma unroll
            for (int c = 0; c < 16; ++c) {
                float w = hi_f(uu[h * 16 + c]);
                s0 = fmaf(lo_f(t[c].x), w, s0);
                s1 = fmaf(hi_f(t[c].x), w, s1);
                s2 = fmaf(lo_f(t[c].y), w, s2);
                s3 = fmaf(hi_f(t[c].y), w, s3);
            }
        }
        uint2 o;
        o.x = cvtpk(s0, s1);
        o.y = cvtpk(s2, s3);
        nm4[s] = o;
    }
    __syncthreads();
}

// root: 128 threads (32 children x 4 cols), shfl-xor reduce within 32-groups.
template <typename NMP>
static __device__ __forceinline__ void do_root(NMP nm4, const ushort4* __restrict__ rpk,
                                               float* __restrict__ out, int b0, int tid) {
    const char* nmB = (const char*)nm4;
    if (tid < 128) {
        int col = tid >> 5, c = tid & 31;
        ushort4 r = rpk[c];
        int woff = (col >> 1) << 2;  // which u32 word holds this column pair
        unsigned int wa = *(const unsigned int*)(nmB + r.x + woff);
        unsigned int wb = *(const unsigned int*)(nmB + r.y + woff);
        float va = (col & 1) ? hi_f(wa) : lo_f(wa);
        float vb = (col & 1) ? hi_f(wb) : lo_f(wb);
        float su = va * vb * bf2f(r.z);
        #pragma unroll
        for (int d = 16; d; d >>= 1) su += __shfl_xor(su, d);
        if (c == 0) out[b0 + col] = (flog2(su) - ROOT_LOG2_SCALE) * LN2;
    }
}

// ---------------------------------------------------------------------------
// mega A: block owns 4 batch cols; em AND nm slices in LDS (135 KB, dynamic
// opt-in). em at LDS offset 0 so the hot sum-gathers fold their base.
// 1024 threads, launch_bounds(1024,4) pins VGPR<=128 (16 waves/CU kept).
// ---------------------------------------------------------------------------
__global__ void __launch_bounds__(1024, 4) k_mega_lds(
        const int* __restrict__ x, const unsigned short* __restrict__ lpT,
        const unsigned int* __restrict__ ppk, const unsigned int* __restrict__ spk,
        const ushort4* __restrict__ rpk, float* __restrict__ out) {
    extern __shared__ uint2 smem2[];
    uint2* em4 = smem2;                   // [8192] = 64 KB (offset 0: hot gathers)
    uint2* nm4 = smem2 + 8192;            // [8192] = 64 KB
    int* xv = (int*)(smem2 + 16384);      // [4][256] = 4 KB
    int tid = threadIdx.x;
    int b0 = blockIdx.x * 4;

    {
        int c = tid >> 8, v = tid & 255;
        xv[tid] = x[(b0 + c) * VV + v];
    }
    __syncthreads();
    for (int i = tid; i < N0; i += 1024) {   // input gather via transposed lpT
        int v = i >> 5;
        unsigned int a = lpT[(size_t)xv[v]       * N0 + i];
        unsigned int b = lpT[(size_t)xv[256 + v] * N0 + i];
        unsigned int c = lpT[(size_t)xv[512 + v] * N0 + i];
        unsigned int d = lpT[(size_t)xv[768 + v] * N0 + i];
        uint2 o;
        o.x = a | (b << 16);
        o.y = c | (d << 16);
        nm4[i] = o;
    }
    __syncthreads();
    do_layer(nm4, em4, ppk,         spk,          8192, 4096, tid, 1024);
    do_layer(nm4, em4, ppk + 8192,  spk + 131072, 4096, 2048, tid, 1024);
    do_layer(nm4, em4, ppk + 12288, spk + 196608, 2048, 1024, tid, 1024);
    do_root(nm4, rpk, out, b0, tid);
}

// ---------------------------------------------------------------------------
// mega B (fallback if >64KB LDS opt-in fails): em in LDS (64 KB), nm in a
// per-block global slice.
// ---------------------------------------------------------------------------
__global__ void __launch_bounds__(1024, 4) k_mega_glb(
        const int* __restrict__ x, const unsigned short* __restrict__ lpT,
        const unsigned int* __restrict__ ppk, const unsigned int* __restrict__ spk,
        const ushort4* __restrict__ rpk, uint2* __restrict__ nmg,
        float* __restrict__ out) {
    extern __shared__ uint2 smem2[];
    uint2* em4 = smem2;                                // [8192] = 64 KB
    uint2* nm4 = nmg + (size_t)blockIdx.x * 8192;      // global slice
    int tid = threadIdx.x;
    int b0 = blockIdx.x * 4;

    for (int i = tid; i < N0; i += 1024) {
        int v = i >> 5;
        unsigned int a = lpT[(size_t)x[(b0 + 0) * VV + v] * N0 + i];
        unsigned int b = lpT[(size_t)x[(b0 + 1) * VV + v] * N0 + i];
        unsigned int c = lpT[(size_t)x[(b0 + 2) * VV + v] * N0 + i];
        unsigned int d = lpT[(size_t)x[(b0 + 3) * VV + v] * N0 + i];
        uint2 o;
        o.x = a | (b << 16);
        o.y = c | (d << 16);
        nm4[i] = o;
    }
    __syncthreads();
    do_layer(nm4, em4, ppk,         spk,          8192, 4096, tid, 1024);
    do_layer(nm4, em4, ppk + 8192,  spk + 131072, 4096, 2048, tid, 1024);
    do_layer(nm4, em4, ppk + 12288, spk + 196608, 2048, 1024, tid, 1024);
    do_root(nm4, rpk, out, b0, tid);
}

// ---------------------------------------------------------------------------
// Launch: 2 dispatches (prep + mega). Deterministic A/B pick by whether the
// 135 KB dynamic-LDS opt-in succeeds.
// ---------------------------------------------------------------------------
extern "C" void kernel_launch(void* const* d_in, const int* in_sizes, int n_in,
                              void* d_out, int out_size, void* d_ws, size_t ws_size,
                              hipStream_t stream) {
    const int*   x         = (const int*)  d_in[0];
    const float* in_logits = (const float*)d_in[1];
    const float* w1        = (const float*)d_in[2];
    const float* w2        = (const float*)d_in[3];
    const float* w3        = (const float*)d_in[4];
    const float* w4        = (const float*)d_in[5];
    const int*   pids1     = (const int*)  d_in[6];
    const int*   pids2     = (const int*)  d_in[7];
    const int*   pids3     = (const int*)  d_in[8];
    const int*   pids4     = (const int*)  d_in[9];
    const int*   cids1     = (const int*)  d_in[10];
    const int*   cids2     = (const int*)  d_in[11];
    const int*   cids3     = (const int*)  d_in[12];
    const int*   cids4     = (const int*)  d_in[13];
    float* out = (float*)d_out;

    char* ws = (char*)d_ws;
    unsigned short* lpT = (unsigned short*)ws;                    // 64*8192 bf16 = 1 MB
    unsigned int*   ppk = (unsigned int*)(ws + 1048576);          // 14336 u32
    unsigned int*   spk = (unsigned int*)(ws + 1105920);          // 229376 u32
    ushort4*        rpk = (ushort4*)(ws + 2023424);               // 32 x 8 B
    uint2*          nmg = (uint2*)(ws + 2023936);                 // 256*8192*8 B = 16 MB (B only)

    k_prep<<<975, 256, 0, stream>>>(in_logits, w1, w2, w3, w4,
                                    cids1, cids2, cids3, cids4,
                                    pids1, pids2, pids3, pids4,
                                    lpT, ppk, spk, rpk);

    const int SMEM_A = 135168;  // 64K em + 64K nm + 4K xv
    const int SMEM_B = 65536;   // 64K em
    hipError_t e = hipFuncSetAttribute((const void*)k_mega_lds,
                                       hipFuncAttributeMaxDynamicSharedMemorySize, SMEM_A);
    if (e == hipSuccess) {
        k_mega_lds<<<256, 1024, SMEM_A, stream>>>(x, lpT, ppk, spk, rpk, out);
    } else {
        (void)hipGetLastError();  // clear sticky error from failed opt-in
        hipFuncSetAttribute((const void*)k_mega_glb,
                            hipFuncAttributeMaxDynamicSharedMemorySize, SMEM_B);
        k_mega_glb<<<256, 1024, SMEM_B, stream>>>(x, lpT, ppk, spk, rpk, nmg, out);
    }
}